// Round 1
// baseline (446.268 us; speedup 1.0000x reference)
//
#include <hip/hip_runtime.h>
#include <math.h>

#define KDIM 100
#define DDIM 64

struct Weights {
  const float *w1, *b1, *w2, *b2, *w3, *b3, *w4, *b4, *w5, *b5;
};

// ---------------- LDS layout (floats) ----------------
constexpr int OFF_USUM = 0;    // [100]
constexpr int OFF_ISUM = 100;  // [100]
constexpr int OFF_US   = 200;  // [100]
constexpr int OFF_IS   = 300;  // [100]
constexpr int OFF_PU   = 400;  // p_u/p_i/q_u/q_i contiguous [4][100]
constexpr int OFF_W    = 800;
// per-net weight block (even offsets so float2 LDS reads stay 8B-aligned):
constexpr int W2O = 0;     // [100][50]
constexpr int W3O = 5000;  // [50][26]  (padded; col 25 = 0)
constexpr int W4O = 6300;  // [25][12]
constexpr int W5O = 6600;  // [12]
constexpr int B1O = 6612;  // [100]
constexpr int B2O = 6712;  // [50]
constexpr int B3O = 6762;  // [25]
constexpr int B4O = 6787;  // [12]
constexpr int B5O = 6799;  // [1]
constexpr int NW  = 6800;
constexpr int OFF_C = OFF_W + 2 * NW;   // 14400, [128] partial c sums
constexpr int SMEM_TOT = OFF_C + 128;   // 14528 floats = 58.1 KB

// ---------------- kernel 1: embedding row sums ----------------
__global__ void rowsum_kernel(const float* __restrict__ user_emb,
                              const float* __restrict__ item_emb,
                              float* __restrict__ u_rowsum,
                              float* __restrict__ i_rowsum,
                              int NU, int NI) {
  const int r = blockIdx.x * blockDim.x + threadIdx.x;
  if (r >= NU + NI) return;
  const float* src = (r < NU) ? (user_emb + (size_t)r * DDIM)
                              : (item_emb + (size_t)(r - NU) * DDIM);
  float s = 0.f;
  #pragma unroll
  for (int i = 0; i < DDIM / 4; ++i) {
    const float4 v = ((const float4*)src)[i];
    s += v.x + v.y + v.z + v.w;
  }
  if (r < NU) u_rowsum[r] = s;
  else        i_rowsum[r - NU] = s;
}

// ---------------- kernel 2: fused per-batch pipeline ----------------
__global__ void __launch_bounds__(256) fused_kernel(
    const int* __restrict__ user_idxs, const int* __restrict__ item_idxs,
    const int* __restrict__ uidx_t, const int* __restrict__ iidx_t,
    const float* __restrict__ uscr, const float* __restrict__ iscr,
    const float* __restrict__ u_rowsum, const float* __restrict__ i_rowsum,
    Weights N1, Weights N2, float* __restrict__ out)
{
  __shared__ float sm[SMEM_TOT];
  const int tid = threadIdx.x;
  const int b = blockIdx.x;

  // ---- gathers: per-batch 4 x 100 vectors
  if (tid < KDIM) {
    const int ub = user_idxs[b];
    const int idx = uidx_t[(size_t)ub * KDIM + tid];
    sm[OFF_USUM + tid] = u_rowsum[idx];
    sm[OFF_US + tid]   = uscr[(size_t)ub * KDIM + tid];
  } else if (tid >= 128 && tid < 128 + KDIM) {
    const int t = tid - 128;
    const int ib = item_idxs[b];
    const int idx = iidx_t[(size_t)ib * KDIM + t];
    sm[OFF_ISUM + t] = i_rowsum[idx];
    sm[OFF_IS + t]   = iscr[(size_t)ib * KDIM + t];
  }

  // ---- stage layer-2..5 weights + biases for both nets into LDS
  for (int s = 0; s < 2; ++s) {
    const Weights& W = s ? N2 : N1;
    const int wb = OFF_W + s * NW;
    for (int e = tid; e < 5000; e += 256) sm[wb + W2O + e] = W.w2[e];
    for (int e = tid; e < 1300; e += 256) {
      const int n = e / 26, m = e % 26;
      sm[wb + W3O + e] = (m < 25) ? W.w3[n * 25 + m] : 0.f;
    }
    for (int e = tid; e < 300; e += 256) sm[wb + W4O + e] = W.w4[e];
    if (tid < 12) sm[wb + W5O + tid] = W.w5[tid];
    for (int e = tid; e < 100; e += 256) sm[wb + B1O + e] = W.b1[e];
    if (tid < 50) sm[wb + B2O + tid] = W.b2[tid];
    if (tid < 25) sm[wb + B3O + tid] = W.b3[tid];
    if (tid < 12) sm[wb + B4O + tid] = W.b4[tid];
    if (tid == 0) sm[wb + B5O] = W.b5[0];
  }
  __syncthreads();

  // ---- phase 2: layer-1 partial projections (400 dots of length 100)
  // p_u[j] = sum_k u_sum[k] W1n1[k][j]      p_i[j] = sum_k i_sum[k] W1n1[100+k][j]
  // q_u[j] = sum_k u_s[k]  W1n2[k][j]       q_i[j] = sum_k i_s[k]  W1n2[100+k][j]
  for (int o = tid; o < 400; o += 256) {
    const int j = o % 100;
    const int which = o / 100;
    const float* w1 = (which < 2) ? N1.w1 : N2.w1;
    const int srcoff = (which == 0) ? OFF_USUM : (which == 1) ? OFF_ISUM
                     : (which == 2) ? OFF_US : OFF_IS;
    const int rowbase = (which & 1) * 100;
    float acc = 0.f;
    for (int k = 0; k < KDIM; ++k)
      acc = fmaf(sm[srcoff + k], w1[(size_t)(rowbase + k) * 100 + j], acc);
    sm[OFF_PU + which * 100 + j] = acc;
  }
  __syncthreads();

  // ---- phase 3: per-row MLP, 2 rows per thread (tid<100), both nets
  if (tid < 100) {
    const int net = tid / 50;          // 0: net1, 1: net2
    const int q = tid % 50;
    const int k0 = 2 * q;
    const int wb = OFF_W + net * NW;
    const int pA = net ? (OFF_PU + 200) : OFF_PU;   // q_u : p_u
    const int pB = pA + 100;                         // q_i : p_i
    const int sAo = net ? OFF_USUM : OFF_US;         // net1 scales by scores
    const int sBo = net ? OFF_ISUM : OFF_IS;         // net2 scales by sums
    const float sA0 = sm[sAo + k0], sA1 = sm[sAo + k0 + 1];
    const float sB0 = sm[sBo + k0], sB1 = sm[sBo + k0 + 1];

    float h2a[50], h2b[50];
    #pragma unroll
    for (int n = 0; n < 50; ++n) { const float bv = sm[wb + B2O + n]; h2a[n] = bv; h2b[n] = bv; }

    for (int j = 0; j < 100; ++j) {
      const float pa = sm[pA + j], pb = sm[pB + j], b1v = sm[wb + B1O + j];
      const float h1a = fmaxf(fmaf(sA0, pa, fmaf(sB0, pb, b1v)), 0.f);
      const float h1b = fmaxf(fmaf(sA1, pa, fmaf(sB1, pb, b1v)), 0.f);
      const float2* w2 = (const float2*)&sm[wb + W2O + j * 50];
      #pragma unroll
      for (int n = 0; n < 25; ++n) {
        const float2 w = w2[n];
        h2a[2*n]   = fmaf(h1a, w.x, h2a[2*n]);
        h2a[2*n+1] = fmaf(h1a, w.y, h2a[2*n+1]);
        h2b[2*n]   = fmaf(h1b, w.x, h2b[2*n]);
        h2b[2*n+1] = fmaf(h1b, w.y, h2b[2*n+1]);
      }
    }

    float h3a[26], h3b[26];
    #pragma unroll
    for (int m = 0; m < 26; ++m) { const float bv = (m < 25) ? sm[wb + B3O + m] : 0.f; h3a[m] = bv; h3b[m] = bv; }
    #pragma unroll
    for (int n = 0; n < 50; ++n) {
      const float va = fmaxf(h2a[n], 0.f), vb = fmaxf(h2b[n], 0.f);
      const float2* w3 = (const float2*)&sm[wb + W3O + n * 26];
      #pragma unroll
      for (int t = 0; t < 13; ++t) {
        const float2 w = w3[t];
        h3a[2*t]   = fmaf(va, w.x, h3a[2*t]);
        h3a[2*t+1] = fmaf(va, w.y, h3a[2*t+1]);
        h3b[2*t]   = fmaf(vb, w.x, h3b[2*t]);
        h3b[2*t+1] = fmaf(vb, w.y, h3b[2*t+1]);
      }
    }

    float h4a[12], h4b[12];
    #pragma unroll
    for (int p = 0; p < 12; ++p) { const float bv = sm[wb + B4O + p]; h4a[p] = bv; h4b[p] = bv; }
    #pragma unroll
    for (int m = 0; m < 25; ++m) {
      const float va = fmaxf(h3a[m], 0.f), vb = fmaxf(h3b[m], 0.f);
      const float2* w4 = (const float2*)&sm[wb + W4O + m * 12];
      #pragma unroll
      for (int t = 0; t < 6; ++t) {
        const float2 w = w4[t];
        h4a[2*t]   = fmaf(va, w.x, h4a[2*t]);
        h4a[2*t+1] = fmaf(va, w.y, h4a[2*t+1]);
        h4b[2*t]   = fmaf(vb, w.x, h4b[2*t]);
        h4b[2*t+1] = fmaf(vb, w.y, h4b[2*t+1]);
      }
    }

    float ca = sm[wb + B5O], cb = ca;
    #pragma unroll
    for (int t = 0; t < 6; ++t) {
      const float2 w = *(const float2*)&sm[wb + W5O + 2*t];
      ca += fmaxf(h4a[2*t], 0.f) * w.x + fmaxf(h4a[2*t+1], 0.f) * w.y;
      cb += fmaxf(h4b[2*t], 0.f) * w.x + fmaxf(h4b[2*t+1], 0.f) * w.y;
    }
    sm[OFF_C + tid] = ca + cb;   // sum of this thread's two rows (c1 or c2)
  }
  __syncthreads();

  if (tid == 0) {
    float s = 0.f;
    for (int t = 0; t < 100; ++t) s += sm[OFF_C + t];
    const float m = s * 0.01f;           // mean over K=100 of (c1+c2)
    out[b] = 1.f / (1.f + expf(-m));
  }
}

extern "C" void kernel_launch(void* const* d_in, const int* in_sizes, int n_in,
                              void* d_out, int out_size, void* d_ws, size_t ws_size,
                              hipStream_t stream) {
  const int*   user_idxs = (const int*)d_in[0];
  const int*   item_idxs = (const int*)d_in[1];
  const int*   uidx_t    = (const int*)d_in[2];
  const int*   iidx_t    = (const int*)d_in[3];
  const float* uscr      = (const float*)d_in[4];
  const float* iscr      = (const float*)d_in[5];
  const float* uemb      = (const float*)d_in[6];
  const float* iemb      = (const float*)d_in[7];

  const int B  = in_sizes[0];
  const int NU = in_sizes[6] / DDIM;
  const int NI = in_sizes[7] / DDIM;

  Weights N1 { (const float*)d_in[8],  (const float*)d_in[9],
               (const float*)d_in[10], (const float*)d_in[11],
               (const float*)d_in[12], (const float*)d_in[13],
               (const float*)d_in[14], (const float*)d_in[15],
               (const float*)d_in[16], (const float*)d_in[17] };
  Weights N2 { (const float*)d_in[18], (const float*)d_in[19],
               (const float*)d_in[20], (const float*)d_in[21],
               (const float*)d_in[22], (const float*)d_in[23],
               (const float*)d_in[24], (const float*)d_in[25],
               (const float*)d_in[26], (const float*)d_in[27] };

  float* u_rowsum = (float*)d_ws;
  float* i_rowsum = u_rowsum + NU;
  float* out = (float*)d_out;

  const int NR = NU + NI;
  rowsum_kernel<<<(NR + 255) / 256, 256, 0, stream>>>(uemb, iemb, u_rowsum, i_rowsum, NU, NI);
  fused_kernel<<<B, 256, 0, stream>>>(user_idxs, item_idxs, uidx_t, iidx_t,
                                      uscr, iscr, u_rowsum, i_rowsum, N1, N2, out);
}

// Round 4
// 212.768 us; speedup vs baseline: 2.0974x; 2.0974x over previous
//
#include <hip/hip_runtime.h>
#include <math.h>

#define KDIM 100
#define DDIM 64

// ---------------- per-net constant-memory layout (floats) ----------------
constexpr int CW2 = 0;      // [100][50]
constexpr int CW3 = 5000;   // [50][25]
constexpr int CW4 = 6250;   // [25][12]
constexpr int CW5 = 6550;   // [12]
constexpr int CB1 = 6562;   // [100]
constexpr int CB2 = 6662;   // [50]
constexpr int CB3 = 6712;   // [25]
constexpr int CB4 = 6737;   // [12]
constexpr int CB5 = 6749;   // [1]
constexpr int CNW = 6750;   // per-net total

__constant__ float CW[2 * CNW];   // 54 KB: layer-2..5 weights+biases, both nets

// ---------------- kernel 1: embedding row sums ----------------
__global__ void rowsum_kernel(const float* __restrict__ user_emb,
                              const float* __restrict__ item_emb,
                              float* __restrict__ u_rowsum,
                              float* __restrict__ i_rowsum,
                              int NU, int NI) {
  const int r = blockIdx.x * blockDim.x + threadIdx.x;
  if (r >= NU + NI) return;
  const float* src = (r < NU) ? (user_emb + (size_t)r * DDIM)
                              : (item_emb + (size_t)(r - NU) * DDIM);
  float s = 0.f;
  #pragma unroll
  for (int i = 0; i < DDIM / 4; ++i) {
    const float4 v = ((const float4*)src)[i];
    s += v.x + v.y + v.z + v.w;
  }
  if (r < NU) u_rowsum[r] = s;
  else        i_rowsum[r - NU] = s;
}

// ---------------- kernel 2: fused gather + projections + MLP ----------------
// LDS layout (floats): 0 USUM,100 ISUM,200 US,300 IS,
//                      400 PA1,500 PB1,600 PA2,700 PB2, 800..803 wave sums
__global__ void __launch_bounds__(256) mlp_kernel(
    const int* __restrict__ user_idxs, const int* __restrict__ item_idxs,
    const int* __restrict__ uidx_t, const int* __restrict__ iidx_t,
    const float* __restrict__ uscr, const float* __restrict__ iscr,
    const float* __restrict__ u_rowsum, const float* __restrict__ i_rowsum,
    const float* __restrict__ n1w1, const float* __restrict__ n2w1,
    float* __restrict__ out)
{
  __shared__ float sm[804];
  const int tid = threadIdx.x;
  const int b = blockIdx.x;

  // ---- gather per-batch vectors
  if (tid < KDIM) {
    const int ub = user_idxs[b];
    const int idx = uidx_t[(size_t)ub * KDIM + tid];
    sm[0 + tid]   = u_rowsum[idx];
    sm[200 + tid] = uscr[(size_t)ub * KDIM + tid];
  } else if (tid >= 128 && tid < 128 + KDIM) {
    const int t = tid - 128;
    const int ib = item_idxs[b];
    const int idx = iidx_t[(size_t)ib * KDIM + t];
    sm[100 + t] = i_rowsum[idx];
    sm[300 + t] = iscr[(size_t)ib * KDIM + t];
  }
  __syncthreads();

  // ---- layer-1 partial projections: 400 dots of length 100
  // PA1 = usum @ W1n1[0:100], PB1 = isum @ W1n1[100:200]
  // PA2 = us   @ W1n2[0:100], PB2 = is   @ W1n2[100:200]
  for (int o = tid; o < 400; o += 256) {
    const int sel = o / 100, j = o % 100;
    const float* w1 = (sel < 2) ? n1w1 : n2w1;
    const int src = (sel == 0) ? 0 : (sel == 1) ? 100 : (sel == 2) ? 200 : 300;
    const int rb = (sel & 1) * KDIM;
    float a0 = 0.f, a1 = 0.f, a2 = 0.f, a3 = 0.f;
    #pragma unroll 4
    for (int k = 0; k < KDIM; k += 4) {
      a0 = fmaf(sm[src + k + 0], w1[(size_t)(rb + k + 0) * KDIM + j], a0);
      a1 = fmaf(sm[src + k + 1], w1[(size_t)(rb + k + 1) * KDIM + j], a1);
      a2 = fmaf(sm[src + k + 2], w1[(size_t)(rb + k + 2) * KDIM + j], a2);
      a3 = fmaf(sm[src + k + 3], w1[(size_t)(rb + k + 3) * KDIM + j], a3);
    }
    sm[400 + sel * 100 + j] = (a0 + a1) + (a2 + a3);
  }
  __syncthreads();

  // ---- MLP: one lane = one row. Waves 0,1 -> net1 rows 0-99; waves 2,3 -> net2.
  const int net = __builtin_amdgcn_readfirstlane(tid >> 7);  // wave-uniform
  const int cb = net * CNW;                                  // uniform -> s_load
  const int row = tid & 127;
  const int rr = (row < KDIM) ? row : 0;
  const float sA = net ? sm[0 + rr]   : sm[200 + rr];  // net1: scores, net2: sums
  const float sB = net ? sm[100 + rr] : sm[300 + rr];
  const int pa0 = net ? 600 : 400;
  const int pb0 = net ? 700 : 500;

  float h2[50];
  #pragma unroll
  for (int n = 0; n < 50; ++n) h2[n] = CW[cb + CB2 + n];

  #pragma unroll 2
  for (int j = 0; j < KDIM; ++j) {
    const float pa = sm[pa0 + j], pb = sm[pb0 + j];
    const float h1 = fmaxf(fmaf(sA, pa, fmaf(sB, pb, CW[cb + CB1 + j])), 0.f);
    #pragma unroll
    for (int n = 0; n < 50; ++n)
      h2[n] = fmaf(h1, CW[cb + CW2 + j * 50 + n], h2[n]);
  }

  float h3[25];
  #pragma unroll
  for (int m = 0; m < 25; ++m) h3[m] = CW[cb + CB3 + m];
  #pragma unroll
  for (int n = 0; n < 50; ++n) {
    const float v = fmaxf(h2[n], 0.f);
    #pragma unroll
    for (int m = 0; m < 25; ++m)
      h3[m] = fmaf(v, CW[cb + CW3 + n * 25 + m], h3[m]);
  }

  float h4[12];
  #pragma unroll
  for (int p = 0; p < 12; ++p) h4[p] = CW[cb + CB4 + p];
  #pragma unroll
  for (int m = 0; m < 25; ++m) {
    const float v = fmaxf(h3[m], 0.f);
    #pragma unroll
    for (int p = 0; p < 12; ++p)
      h4[p] = fmaf(v, CW[cb + CW4 + m * 12 + p], h4[p]);
  }

  float c = CW[cb + CB5];
  #pragma unroll
  for (int t = 0; t < 12; ++t)
    c = fmaf(fmaxf(h4[t], 0.f), CW[cb + CW5 + t], c);
  if (row >= KDIM) c = 0.f;

  // ---- reduce 200 row values -> sigmoid(mean)
  #pragma unroll
  for (int off = 32; off; off >>= 1) c += __shfl_down(c, off);
  if ((tid & 63) == 0) sm[800 + (tid >> 6)] = c;
  __syncthreads();
  if (tid == 0) {
    const float s = sm[800] + sm[801] + sm[802] + sm[803];
    out[b] = 1.f / (1.f + expf(-0.01f * s));
  }
}

extern "C" void kernel_launch(void* const* d_in, const int* in_sizes, int n_in,
                              void* d_out, int out_size, void* d_ws, size_t ws_size,
                              hipStream_t stream) {
  const int*   user_idxs = (const int*)d_in[0];
  const int*   item_idxs = (const int*)d_in[1];
  const int*   uidx_t    = (const int*)d_in[2];
  const int*   iidx_t    = (const int*)d_in[3];
  const float* uscr      = (const float*)d_in[4];
  const float* iscr      = (const float*)d_in[5];
  const float* uemb      = (const float*)d_in[6];
  const float* iemb      = (const float*)d_in[7];

  const int B  = in_sizes[0];
  const int NU = in_sizes[6] / DDIM;
  const int NI = in_sizes[7] / DDIM;

  // stage layer-2..5 weights+biases of both nets into __constant__ CW (d2d async)
  void* cw_dev = nullptr;
  hipGetSymbolAddress(&cw_dev, HIP_SYMBOL(CW));
  float* cw = (float*)cw_dev;
  for (int net = 0; net < 2; ++net) {
    const int base = 8 + net * 10;  // d_in[8..17] = net1, d_in[18..27] = net2
    const float* b1 = (const float*)d_in[base + 1];
    const float* w2 = (const float*)d_in[base + 2];
    const float* b2 = (const float*)d_in[base + 3];
    const float* w3 = (const float*)d_in[base + 4];
    const float* b3 = (const float*)d_in[base + 5];
    const float* w4 = (const float*)d_in[base + 6];
    const float* b4 = (const float*)d_in[base + 7];
    const float* w5 = (const float*)d_in[base + 8];
    const float* b5 = (const float*)d_in[base + 9];
    float* nb = cw + net * CNW;
    hipMemcpyAsync(nb + CW2, w2, 5000 * 4, hipMemcpyDeviceToDevice, stream);
    hipMemcpyAsync(nb + CW3, w3, 1250 * 4, hipMemcpyDeviceToDevice, stream);
    hipMemcpyAsync(nb + CW4, w4,  300 * 4, hipMemcpyDeviceToDevice, stream);
    hipMemcpyAsync(nb + CW5, w5,   12 * 4, hipMemcpyDeviceToDevice, stream);
    hipMemcpyAsync(nb + CB1, b1,  100 * 4, hipMemcpyDeviceToDevice, stream);
    hipMemcpyAsync(nb + CB2, b2,   50 * 4, hipMemcpyDeviceToDevice, stream);
    hipMemcpyAsync(nb + CB3, b3,   25 * 4, hipMemcpyDeviceToDevice, stream);
    hipMemcpyAsync(nb + CB4, b4,   12 * 4, hipMemcpyDeviceToDevice, stream);
    hipMemcpyAsync(nb + CB5, b5,    1 * 4, hipMemcpyDeviceToDevice, stream);
  }

  float* u_rowsum = (float*)d_ws;
  float* i_rowsum = u_rowsum + NU;
  float* out = (float*)d_out;

  const int NR = NU + NI;
  rowsum_kernel<<<(NR + 255) / 256, 256, 0, stream>>>(uemb, iemb, u_rowsum, i_rowsum, NU, NI);
  mlp_kernel<<<B, 256, 0, stream>>>(user_idxs, item_idxs, uidx_t, iidx_t,
                                    uscr, iscr, u_rowsum, i_rowsum,
                                    (const float*)d_in[8], (const float*)d_in[18], out);
}